// Round 3
// baseline (53.645 us; speedup 1.0000x reference)
//
#include <hip/hip_runtime.h>

#define BB 128
#define SS 512
#define HH 1024
#define NB 16   // sum-pass blocks per batch

typedef float f32x4 __attribute__((ext_vector_type(4)));

// ---------------------------------------------------------------------------
// Per-block meta recompute: int4 {t_begin, t_end, l_begin, l_end} for batch b.
// 256 threads. Exactly-3-SEP data makes the thread-0 scan ~10 instructions.
// ---------------------------------------------------------------------------
__device__ __forceinline__ int4 compute_meta(const int* __restrict__ ids,
                                             const int* __restrict__ attn,
                                             int b, int sep) {
    __shared__ unsigned long long words[SS / 64];
    __shared__ int sh_p[4];      // p1, p2, p3, cnt
    __shared__ int sh_mask;
    const int t = threadIdx.x;   // 0..255
    const int* row = ids + b * SS;
    const int tok0 = row[t];
    const int tok1 = row[t + 256];
    const unsigned long long b0 = __ballot(tok0 == sep);
    const unsigned long long b1 = __ballot(tok1 == sep);
    if ((t & 63) == 0) {
        words[t >> 6] = b0;
        words[4 + (t >> 6)] = b1;
    }
    if (t == 0) sh_mask = 0;
    __syncthreads();
    if (t == 0) {
        int cnt = 0, p1 = 0, p2 = 0, p3 = 0;
        for (int i = 0; i < SS / 64; ++i) {
            unsigned long long word = words[i];
            while (word && cnt < 3) {
                const int pos = i * 64 + __builtin_ctzll(word);
                ++cnt;
                if (cnt == 1) p1 = pos;
                else if (cnt == 2) p2 = pos;
                else p3 = pos;
                word &= word - 1;
            }
        }
        sh_p[0] = p1; sh_p[1] = p2; sh_p[2] = p3; sh_p[3] = cnt;
    }
    __syncthreads();
    const int cnt = sh_p[3];
    if (cnt < 3) {   // block-uniform rare branch: mask_len fallback
        const int* arow = attn + b * SS;
        atomicAdd(&sh_mask, arow[t] + arow[t + 256]);
        __syncthreads();
    }
    int4 m;
    if (cnt >= 2) {
        m.x = 1;
        m.y = max(sh_p[0], 1);           // title [1, p1)
        m.z = sh_p[1] + 1;               // lead begin
        const int e = (cnt >= 3) ? sh_p[2] : sh_mask;
        m.w = max(e, m.z);               // lead end (clamped)
    } else {
        m.x = 0; m.y = 0; m.z = 0; m.w = 0;
    }
    return m;
}

// first lead-union index owned by block nb (validity: u0 < T)
__device__ __forceinline__ int lead_first_u(int t_len, int nb) {
    int d = nb - (t_len % NB);
    if (d < 0) d += NB;
    return t_len + d;
}

// ---------------------------------------------------------------------------
// Kernel 1: balanced partial sums. grid = (NB, BB), 256 threads.
// Union-span index u in [0, T): u < t_len -> title row 1+u,
// else lead row m.z + (u - t_len). Block nb owns u = nb, nb+NB, ...
// Writes partials[b][nb][2][HH] only for the halves it touched; the
// finalize kernel derives the same touch-predicates, so poisoned ws is
// never read.
// ---------------------------------------------------------------------------
__global__ void seg_sum_balanced(const float* __restrict__ hs,
                                 const int* __restrict__ ids,
                                 const int* __restrict__ attn,
                                 const int* __restrict__ sep_tok,
                                 float* __restrict__ partials) {
    const int nb = blockIdx.x;
    const int b  = blockIdx.y;
    const int4 m = compute_meta(ids, attn, b, sep_tok[0]);
    const int t_len = m.y - m.x;
    const int l_len = m.w - m.z;
    const int T = t_len + l_len;

    const int h4 = threadIdx.x;
    const f32x4* base = (const f32x4*)(hs + (size_t)b * SS * HH);
    f32x4* p = (f32x4*)(partials + (size_t)(b * NB + nb) * 2 * HH);

    // title rows owned by this block
    if (nb < t_len) {
        f32x4 a = {0.f, 0.f, 0.f, 0.f};
        #pragma unroll 2
        for (int u = nb; u < t_len; u += NB) {
            const int s = m.x + u;
            a += __builtin_nontemporal_load(&base[(size_t)s * (HH / 4) + h4]);
        }
        p[h4] = a;
    }
    // lead rows owned by this block
    const int u0 = lead_first_u(t_len, nb);
    if (u0 < T) {
        f32x4 a = {0.f, 0.f, 0.f, 0.f};
        #pragma unroll 2
        for (int u = u0; u < T; u += NB) {
            const int s = m.z + (u - t_len);
            a += __builtin_nontemporal_load(&base[(size_t)s * (HH / 4) + h4]);
        }
        p[HH / 4 + h4] = a;
    }
}

// ---------------------------------------------------------------------------
// Kernel 2: gather valid partials + divide / CLS fallback. grid = (2, BB).
// ---------------------------------------------------------------------------
__global__ void seg_final_balanced(const float* __restrict__ hs,
                                   const int* __restrict__ ids,
                                   const int* __restrict__ attn,
                                   const int* __restrict__ sep_tok,
                                   const float* __restrict__ partials,
                                   float* __restrict__ out) {
    const int span = blockIdx.x;   // 0 = title, 1 = lead
    const int b = blockIdx.y;
    const int4 m = compute_meta(ids, attn, b, sep_tok[0]);
    const int h4 = threadIdx.x;
    const int t_len = m.y - m.x;
    const int l_len = m.w - m.z;
    const int T = t_len + l_len;

    f32x4 a = {0.f, 0.f, 0.f, 0.f};
    int cntr;
    if (span == 0) {
        cntr = t_len;
        const int lim = min(t_len, NB);
        for (int nb = 0; nb < lim; ++nb) {
            const f32x4* p = (const f32x4*)(partials + (size_t)(b * NB + nb) * 2 * HH);
            a += p[h4];
        }
    } else {
        cntr = l_len;
        #pragma unroll
        for (int nb = 0; nb < NB; ++nb) {
            if (lead_first_u(t_len, nb) < T) {
                const f32x4* p = (const f32x4*)(partials + (size_t)(b * NB + nb) * 2 * HH);
                a += p[HH / 4 + h4];
            }
        }
    }

    f32x4 o;
    if (cntr > 0) {
        const float c = (float)cntr;
        o = a / c;
    } else {
        o = ((const f32x4*)(hs + (size_t)b * SS * HH))[h4];  // CLS row
    }
    ((f32x4*)out)[(size_t)(span * BB + b) * (HH / 4) + h4] = o;
}

// ---------------------------------------------------------------------------
extern "C" void kernel_launch(void* const* d_in, const int* in_sizes, int n_in,
                              void* d_out, int out_size, void* d_ws, size_t ws_size,
                              hipStream_t stream) {
    const float* hs  = (const float*)d_in[0];
    const int*   ids = (const int*)d_in[1];
    const int*   am  = (const int*)d_in[2];
    const int*   sep = (const int*)d_in[3];
    float* out = (float*)d_out;
    float* partials = (float*)d_ws;   // BB*NB*2*HH floats = 16 MB (ws is ~1 GiB)

    seg_sum_balanced<<<dim3(NB, BB), 256, 0, stream>>>(hs, ids, am, sep, partials);
    seg_final_balanced<<<dim3(2, BB), 256, 0, stream>>>(hs, ids, am, sep, partials, out);
}

// Round 4
// 43.753 us; speedup vs baseline: 1.2261x; 1.2261x over previous
//
#include <hip/hip_runtime.h>

#define BB 128
#define SS 512
#define HH 1024
#define NB 16   // sum-pass blocks per batch

typedef float f32x4 __attribute__((ext_vector_type(4)));

// ---------------------------------------------------------------------------
// Per-block meta recompute: int4 {t_begin, t_end, l_begin, l_end} for batch b.
// 256 threads. Exactly-3-SEP data makes the thread-0 scan ~10 instructions.
// ---------------------------------------------------------------------------
__device__ __forceinline__ int4 compute_meta(const int* __restrict__ ids,
                                             const int* __restrict__ attn,
                                             int b, int sep) {
    __shared__ unsigned long long words[SS / 64];
    __shared__ int sh_p[4];      // p1, p2, p3, cnt
    __shared__ int sh_mask;
    const int t = threadIdx.x;   // 0..255
    const int* row = ids + b * SS;
    const int tok0 = row[t];
    const int tok1 = row[t + 256];
    const unsigned long long b0 = __ballot(tok0 == sep);
    const unsigned long long b1 = __ballot(tok1 == sep);
    if ((t & 63) == 0) {
        words[t >> 6] = b0;
        words[4 + (t >> 6)] = b1;
    }
    if (t == 0) sh_mask = 0;
    __syncthreads();
    if (t == 0) {
        int cnt = 0, p1 = 0, p2 = 0, p3 = 0;
        for (int i = 0; i < SS / 64; ++i) {
            unsigned long long word = words[i];
            while (word && cnt < 3) {
                const int pos = i * 64 + __builtin_ctzll(word);
                ++cnt;
                if (cnt == 1) p1 = pos;
                else if (cnt == 2) p2 = pos;
                else p3 = pos;
                word &= word - 1;
            }
        }
        sh_p[0] = p1; sh_p[1] = p2; sh_p[2] = p3; sh_p[3] = cnt;
    }
    __syncthreads();
    const int cnt = sh_p[3];
    if (cnt < 3) {   // block-uniform rare branch: mask_len fallback
        const int* arow = attn + b * SS;
        atomicAdd(&sh_mask, arow[t] + arow[t + 256]);
        __syncthreads();
    }
    int4 m;
    if (cnt >= 2) {
        m.x = 1;
        m.y = max(sh_p[0], 1);           // title [1, p1)
        m.z = sh_p[1] + 1;               // lead begin
        const int e = (cnt >= 3) ? sh_p[2] : sh_mask;
        m.w = max(e, m.z);               // lead end (clamped)
    } else {
        m.x = 0; m.y = 0; m.z = 0; m.w = 0;
    }
    return m;
}

// ---------------------------------------------------------------------------
// Kernel 1: balanced CONTIGUOUS partial sums. grid = (BB, NB), 256 threads.
// Union index u in [0, T): u < t_len -> title row m.x+u, else lead row
// m.z + (u - t_len). Block nb owns the contiguous range [nb*T/NB, (nb+1)*T/NB).
// grid.x = batch so consecutive blocks (-> consecutive CUs) hold different
// batches: per-CU work averages over 8 batches.
// Writes partials[b][nb][2][HH] only for the halves it touched; finalize
// derives identical touch-predicates, so poisoned ws is never read.
// ---------------------------------------------------------------------------
__global__ void seg_sum_balanced(const float* __restrict__ hs,
                                 const int* __restrict__ ids,
                                 const int* __restrict__ attn,
                                 const int* __restrict__ sep_tok,
                                 float* __restrict__ partials) {
    const int b  = blockIdx.x;
    const int nb = blockIdx.y;
    const int4 m = compute_meta(ids, attn, b, sep_tok[0]);
    const int t_len = m.y - m.x;
    const int l_len = m.w - m.z;
    const int T = t_len + l_len;

    const int u0 = (nb * T) / NB;
    const int u1 = ((nb + 1) * T) / NB;

    const int h4 = threadIdx.x;
    const f32x4* base = (const f32x4*)(hs + (size_t)b * SS * HH);
    f32x4* p = (f32x4*)(partials + (size_t)(b * NB + nb) * 2 * HH);

    // title part of this block's union range
    const int tA = u0, tB = min(u1, t_len);
    if (tA < tB) {
        f32x4 a = {0.f, 0.f, 0.f, 0.f};
        #pragma unroll 4
        for (int u = tA; u < tB; ++u) {
            const int s = m.x + u;
            a += base[(size_t)s * (HH / 4) + h4];
        }
        p[h4] = a;
    }
    // lead part of this block's union range
    const int lA = max(u0, t_len), lB = u1;
    if (lA < lB) {
        f32x4 a = {0.f, 0.f, 0.f, 0.f};
        #pragma unroll 4
        for (int u = lA; u < lB; ++u) {
            const int s = m.z + (u - t_len);
            a += base[(size_t)s * (HH / 4) + h4];
        }
        p[HH / 4 + h4] = a;
    }
}

// ---------------------------------------------------------------------------
// Kernel 2: gather valid partials + divide / CLS fallback. grid = (2, BB).
// ---------------------------------------------------------------------------
__global__ void seg_final_balanced(const float* __restrict__ hs,
                                   const int* __restrict__ ids,
                                   const int* __restrict__ attn,
                                   const int* __restrict__ sep_tok,
                                   const float* __restrict__ partials,
                                   float* __restrict__ out) {
    const int span = blockIdx.x;   // 0 = title, 1 = lead
    const int b = blockIdx.y;
    const int4 m = compute_meta(ids, attn, b, sep_tok[0]);
    const int h4 = threadIdx.x;
    const int t_len = m.y - m.x;
    const int l_len = m.w - m.z;
    const int T = t_len + l_len;

    f32x4 a = {0.f, 0.f, 0.f, 0.f};
    const int cntr = (span == 0) ? t_len : l_len;

    #pragma unroll
    for (int nb = 0; nb < NB; ++nb) {
        const int u0 = (nb * T) / NB;
        const int u1 = ((nb + 1) * T) / NB;
        bool valid;
        if (span == 0) valid = u0 < min(u1, t_len);
        else           valid = max(u0, t_len) < u1;
        if (valid) {
            const f32x4* p = (const f32x4*)(partials +
                (size_t)(b * NB + nb) * 2 * HH + (size_t)span * HH);
            a += p[h4];
        }
    }

    f32x4 o;
    if (cntr > 0) {
        o = a / (float)cntr;
    } else {
        o = ((const f32x4*)(hs + (size_t)b * SS * HH))[h4];  // CLS row
    }
    ((f32x4*)out)[(size_t)(span * BB + b) * (HH / 4) + h4] = o;
}

// ---------------------------------------------------------------------------
extern "C" void kernel_launch(void* const* d_in, const int* in_sizes, int n_in,
                              void* d_out, int out_size, void* d_ws, size_t ws_size,
                              hipStream_t stream) {
    const float* hs  = (const float*)d_in[0];
    const int*   ids = (const int*)d_in[1];
    const int*   am  = (const int*)d_in[2];
    const int*   sep = (const int*)d_in[3];
    float* out = (float*)d_out;
    float* partials = (float*)d_ws;   // BB*NB*2*HH floats = 16 MB (ws is ~1 GiB)

    seg_sum_balanced<<<dim3(BB, NB), 256, 0, stream>>>(hs, ids, am, sep, partials);
    seg_final_balanced<<<dim3(2, BB), 256, 0, stream>>>(hs, ids, am, sep, partials, out);
}